// Round 5
// baseline (608.885 us; speedup 1.0000x reference)
//
#include <hip/hip_runtime.h>
#include <stdint.h>

typedef __bf16 bf16_t;
typedef __bf16 bf16x8 __attribute__((ext_vector_type(8)));
typedef __bf16 bf16x4 __attribute__((ext_vector_type(4)));
typedef float f32x4 __attribute__((ext_vector_type(4)));

#define S_LEN 2048
#define NH 32
#define NKV 8
#define HD 128
#define B_SZ 2
#define HID 4096
#define QKV_N 6144
#define INFF __builtin_inff()

// global -> LDS direct copy, 16B per lane. LDS dest must be wave-uniform base + lane*16.
__device__ __forceinline__ void gload_lds16(const void* g, void* l) {
    __builtin_amdgcn_global_load_lds(
        (const __attribute__((address_space(1))) void*)(uintptr_t)g,
        (__attribute__((address_space(3))) void*)(uint32_t)(uintptr_t)l,
        16, 0, 0);
}

// ---------------- fp32 -> bf16 convert ----------------
__global__ __launch_bounds__(256) void f2b_kernel(const float4* __restrict__ in,
                                                  bf16x4* __restrict__ out, int n4) {
    int i = blockIdx.x * blockDim.x + threadIdx.x;
    if (i >= n4) return;
    float4 v = in[i];
    bf16x4 o = {(bf16_t)v.x, (bf16_t)v.y, (bf16_t)v.z, (bf16_t)v.w};
    out[i] = o;
}

// ---------------- GEMM 128x256 tile, 4 waves, ring-3 slots, counted vmcnt ----------------
// C[M,N] = A[M,K] @ W[N,K]^T.  BK=32. Slot = A 128x32 (8KB) + B 256x32 (16KB) = 24KB; x3 = 72KB.
// 6 stage-loads/thread/tile (A:2, B:4), staged 2 tiles ahead -> steady-state vmcnt(6).
#define SLOT3 12288   // elems per slot (A 4096 + B 8192)

#define GT(CB, SB, STAGE, VMW) do {                                                        \
    bf16x8 af[8], b01[2];                                                                  \
    _Pragma("unroll") for (int i = 0; i < 8; ++i)                                          \
        af[i] = *(const bf16x8*)&lds[(CB) + offA[i]];                                      \
    b01[0] = *(const bf16x8*)&lds[(CB) + offB[0]];                                         \
    b01[1] = *(const bf16x8*)&lds[(CB) + offB[1]];                                         \
    if (STAGE) {                                                                           \
        gload_lds16(sA0, &lds[(SB) + cA0 * 8]); gload_lds16(sA1, &lds[(SB) + cA1 * 8]);    \
        sA0 += 32; sA1 += 32;                                                              \
    }                                                                                      \
    __builtin_amdgcn_s_barrier();                                                          \
    asm volatile("s_waitcnt lgkmcnt(0)" ::: "memory");                                     \
    __builtin_amdgcn_sched_barrier(0);                                                     \
    __builtin_amdgcn_s_setprio(1);                                                         \
    _Pragma("unroll") for (int i = 0; i < 8; ++i) {                                        \
        acc[i][0] = __builtin_amdgcn_mfma_f32_16x16x32_bf16(af[i], b01[0], acc[i][0], 0, 0, 0); \
        acc[i][1] = __builtin_amdgcn_mfma_f32_16x16x32_bf16(af[i], b01[1], acc[i][1], 0, 0, 0); \
    }                                                                                      \
    __builtin_amdgcn_s_setprio(0);                                                         \
    __builtin_amdgcn_s_barrier();                                                          \
    bf16x8 b23[2];                                                                         \
    b23[0] = *(const bf16x8*)&lds[(CB) + offB[2]];                                         \
    b23[1] = *(const bf16x8*)&lds[(CB) + offB[3]];                                         \
    if (STAGE) {                                                                           \
        gload_lds16(sB0, &lds[(SB) + 4096 + cB0 * 8]);                                     \
        gload_lds16(sB1, &lds[(SB) + 4096 + cB1 * 8]);                                     \
        gload_lds16(sB2, &lds[(SB) + 4096 + cB2 * 8]);                                     \
        gload_lds16(sB3, &lds[(SB) + 4096 + cB3 * 8]);                                     \
        sB0 += 32; sB1 += 32; sB2 += 32; sB3 += 32;                                        \
    }                                                                                      \
    __builtin_amdgcn_s_barrier();                                                          \
    asm volatile("s_waitcnt lgkmcnt(0)" ::: "memory");                                     \
    __builtin_amdgcn_sched_barrier(0);                                                     \
    __builtin_amdgcn_s_setprio(1);                                                         \
    _Pragma("unroll") for (int i = 0; i < 8; ++i) {                                        \
        acc[i][2] = __builtin_amdgcn_mfma_f32_16x16x32_bf16(af[i], b23[0], acc[i][2], 0, 0, 0); \
        acc[i][3] = __builtin_amdgcn_mfma_f32_16x16x32_bf16(af[i], b23[1], acc[i][3], 0, 0, 0); \
    }                                                                                      \
    __builtin_amdgcn_s_setprio(0);                                                         \
    if ((VMW) == 6)      asm volatile("s_waitcnt vmcnt(6)" ::: "memory");                  \
    else if ((VMW) == 0) asm volatile("s_waitcnt vmcnt(0)" ::: "memory");                  \
    __builtin_amdgcn_s_barrier();                                                          \
} while (0)

template<bool F32OUT>
__global__ __launch_bounds__(256, 2) void gemm128(const bf16_t* __restrict__ A,
                                                  const bf16_t* __restrict__ W,
                                                  void* __restrict__ Cv,
                                                  int M, int N, int K) {
    __shared__ __align__(16) bf16_t lds[3 * SLOT3];   // 72KB -> 2 blocks/CU
    const int tid = threadIdx.x;
    const int lane = tid & 63;
    const int wn = tid >> 6;             // 4 waves, each owns 64 cols
    const int l15 = lane & 15, lg = lane >> 4;

    // XCD-aware block swizzle (gridDim.x % 8 == 0)
    const int nbx = N >> 8;
    const int cpx = gridDim.x >> 3;
    const int bid = blockIdx.x;
    const int bid2 = (bid & 7) * cpx + (bid >> 3);
    const int m0 = (bid2 / nbx) * 128;
    const int n0 = (bid2 % nbx) * 256;

    // staging: A 512 chunks (2/thread), B 1024 chunks (4/thread); chunk c -> row=c>>2,
    // src col-chunk (c&3)^((row>>1)&3) (both-sides swizzle); LDS linear at c*16B.
    const int cA0 = tid, cA1 = tid + 256;
    const int cB0 = tid, cB1 = tid + 256, cB2 = tid + 512, cB3 = tid + 768;
    const int rA0 = cA0 >> 2, rA1 = cA1 >> 2;
    const int rB0 = cB0 >> 2, rB1 = cB1 >> 2, rB2 = cB2 >> 2, rB3 = cB3 >> 2;
    const bf16_t* sA0 = A + (size_t)(m0 + rA0) * K + (((cA0 & 3) ^ ((rA0 >> 1) & 3)) * 8);
    const bf16_t* sA1 = A + (size_t)(m0 + rA1) * K + (((cA1 & 3) ^ ((rA1 >> 1) & 3)) * 8);
    const bf16_t* sB0 = W + (size_t)(n0 + rB0) * K + (((cB0 & 3) ^ ((rB0 >> 1) & 3)) * 8);
    const bf16_t* sB1 = W + (size_t)(n0 + rB1) * K + (((cB1 & 3) ^ ((rB1 >> 1) & 3)) * 8);
    const bf16_t* sB2 = W + (size_t)(n0 + rB2) * K + (((cB2 & 3) ^ ((rB2 >> 1) & 3)) * 8);
    const bf16_t* sB3 = W + (size_t)(n0 + rB3) * K + (((cB3 & 3) ^ ((rB3 >> 1) & 3)) * 8);

    // ds_read fragment offsets (elems within slot), same XOR swizzle
    int offA[8], offB[4];
    #pragma unroll
    for (int i = 0; i < 8; ++i) {
        int row = i * 16 + l15;
        offA[i] = row * 32 + ((lg ^ ((row >> 1) & 3)) * 8);
    }
    #pragma unroll
    for (int j = 0; j < 4; ++j) {
        int row = wn * 64 + j * 16 + l15;
        offB[j] = 4096 + row * 32 + ((lg ^ ((row >> 1) & 3)) * 8);
    }

    // prologue: stage tiles 0 and 1 (6 loads each)
    #pragma unroll
    for (int tt = 0; tt < 2; ++tt) {
        const int ss = tt * SLOT3;
        gload_lds16(sA0, &lds[ss + cA0 * 8]); gload_lds16(sA1, &lds[ss + cA1 * 8]);
        gload_lds16(sB0, &lds[ss + 4096 + cB0 * 8]); gload_lds16(sB1, &lds[ss + 4096 + cB1 * 8]);
        gload_lds16(sB2, &lds[ss + 4096 + cB2 * 8]); gload_lds16(sB3, &lds[ss + 4096 + cB3 * 8]);
        sA0 += 32; sA1 += 32; sB0 += 32; sB1 += 32; sB2 += 32; sB3 += 32;
    }
    asm volatile("s_waitcnt vmcnt(6)" ::: "memory");  // tile 0 fully staged
    __builtin_amdgcn_s_barrier();

    f32x4 acc[8][4] = {};
    const int NT = K >> 5;
    int cb = 0, sb = 2 * SLOT3;
    for (int t = 0; t < NT - 2; ++t) {   // stages tiles 2..NT-1
        GT(cb, sb, true, 6);
        cb += SLOT3; if (cb == 3 * SLOT3) cb = 0;
        sb += SLOT3; if (sb == 3 * SLOT3) sb = 0;
    }
    GT(cb, 0, false, 0);
    cb += SLOT3; if (cb == 3 * SLOT3) cb = 0;
    GT(cb, 0, false, -1);

    // epilogue
    #pragma unroll
    for (int i = 0; i < 8; ++i)
        #pragma unroll
        for (int jn = 0; jn < 4; ++jn)
            #pragma unroll
            for (int r = 0; r < 4; ++r) {
                int m = m0 + i * 16 + lg * 4 + r;
                int n = n0 + wn * 64 + jn * 16 + l15;
                float v = acc[i][jn][r];
                if (F32OUT) ((float*)Cv)[(size_t)m * N + n] = v;
                else        ((bf16_t*)Cv)[(size_t)m * N + n] = (bf16_t)v;
            }
}

// ---------------- RoPE (in-place on fused QKV buffer) ----------------
__global__ __launch_bounds__(256) void rope_kernel(bf16_t* __restrict__ QKV,
                                                   const float* __restrict__ cosb,
                                                   const float* __restrict__ sinb) {
    int tid = blockIdx.x * blockDim.x + threadIdx.x;
    int d = tid & 63;
    int h40 = (tid >> 6) % (NH + NKV);
    int bs = tid / (64 * (NH + NKV));
    int col = (h40 < NH) ? h40 * HD : HID + (h40 - NH) * HD;
    bf16_t* rowp = QKV + (size_t)bs * QKV_N + col;
    float x1 = (float)rowp[d];
    float x2 = (float)rowp[d + 64];
    float c1 = cosb[(size_t)bs * HD + d];
    float s1 = sinb[(size_t)bs * HD + d];
    float c2 = cosb[(size_t)bs * HD + d + 64];
    float s2 = sinb[(size_t)bs * HD + d + 64];
    rowp[d]      = (bf16_t)(x1 * c1 - x2 * s1);
    rowp[d + 64] = (bf16_t)(x2 * c2 + x1 * s2);
}

// ---------------- Flash attention: QB=64 (4 waves), KB=64, paired q-tiles ----------------
#define PITCH_P 72

__global__ __launch_bounds__(256, 3) void attn_fwd(const bf16_t* __restrict__ QKV,
                                                   bf16_t* __restrict__ O) {
    __shared__ __align__(16) bf16_t Kl[64 * 128];
    __shared__ __align__(16) bf16_t Vt[128 * 64];
    __shared__ __align__(16) bf16_t Pl[4][16 * PITCH_P];
    const int tid = threadIdx.x;
    const int lane = tid & 63;
    const int w = tid >> 6;
    const int l15 = lane & 15, lg = lane >> 4;
    const int pr = blockIdx.x, h = blockIdx.y, b = blockIdx.z;
    const int kvh = h >> 2;
    const float scale = 0.08838834764831845f;

    int krow[4], kch[4];
    for (int jj = 0; jj < 4; ++jj) { int q = jj * 256 + tid; krow[jj] = q >> 4; kch[jj] = q & 15; }
    const int d0 = (tid >> 4) * 8;
    const int k0v = (tid & 15) * 4;
    const int vci = k0v >> 3;
    const int vsub = k0v & 7;

    const bf16_t* Kb0 = QKV + (size_t)(b * S_LEN) * QKV_N + HID + kvh * HD;
    const bf16_t* Vb0 = QKV + (size_t)(b * S_LEN) * QKV_N + HID + NKV * HD + kvh * HD;
    bf16_t* Plw = Pl[w];

    for (int t = 0; t < 2; ++t) {
        const int qt = (t == 0) ? pr : (31 - pr);
        const int q0 = qt * 64;
        const int qrow = q0 + w * 16 + l15;

        bf16x8 qf[4];
        {
            const bf16_t* qp = QKV + (size_t)(b * S_LEN + qrow) * QKV_N + h * HD;
            for (int c = 0; c < 4; ++c) qf[c] = *(const bf16x8*)&qp[c * 32 + lg * 8];
        }

        f32x4 acc_o[8] = {};
        float mrow = -INFF, lrow = 0.f;
        const int nsteps = qt + 1;

        bf16x8 kst[4], vst[4];
        for (int jj = 0; jj < 4; ++jj)
            kst[jj] = *(const bf16x8*)&Kb0[(size_t)krow[jj] * QKV_N + kch[jj] * 8];
        for (int j2 = 0; j2 < 4; ++j2)
            vst[j2] = *(const bf16x8*)&Vb0[(size_t)(k0v + j2) * QKV_N + d0];

        for (int st = 0; st < nsteps; ++st) {
            const int k0 = st * 64;
            __syncthreads();
            for (int jj = 0; jj < 4; ++jj)
                *(bf16x8*)&Kl[krow[jj] * 128 + ((kch[jj] ^ (krow[jj] & 7)) * 8)] = kst[jj];
            #pragma unroll
            for (int j = 0; j < 8; ++j) {
                bf16x4 cvec = { vst[0][j], vst[1][j], vst[2][j], vst[3][j] };
                *(bf16x4*)&Vt[(d0 + j) * 64 + ((vci ^ j) << 3) + vsub] = cvec;
            }
            __syncthreads();
            if (st + 1 < nsteps) {
                const bf16_t* Kb = Kb0 + (size_t)(k0 + 64) * QKV_N;
                const bf16_t* Vb = Vb0 + (size_t)(k0 + 64) * QKV_N;
                for (int jj = 0; jj < 4; ++jj)
                    kst[jj] = *(const bf16x8*)&Kb[(size_t)krow[jj] * QKV_N + kch[jj] * 8];
                for (int j2 = 0; j2 < 4; ++j2)
                    vst[j2] = *(const bf16x8*)&Vb[(size_t)(k0v + j2) * QKV_N + d0];
            }
            f32x4 s[4];
            #pragma unroll
            for (int nt = 0; nt < 4; ++nt) {
                s[nt] = (f32x4){0.f, 0.f, 0.f, 0.f};
                const int row = nt * 16 + l15;
                const int rb = row * 128, key = row & 7;
                #pragma unroll
                for (int c = 0; c < 4; ++c) {
                    bf16x8 kf = *(const bf16x8*)&Kl[rb + (((c * 4 + lg) ^ key) * 8)];
                    s[nt] = __builtin_amdgcn_mfma_f32_16x16x32_bf16(kf, qf[c], s[nt], 0, 0, 0);
                }
            }
            float ev[4][4];
            float mx = -INFF;
            #pragma unroll
            for (int nt = 0; nt < 4; ++nt)
                #pragma unroll
                for (int r = 0; r < 4; ++r) {
                    int k = k0 + nt * 16 + lg * 4 + r;
                    float v = (k <= qrow) ? s[nt][r] * scale : -INFF;
                    ev[nt][r] = v;
                    mx = fmaxf(mx, v);
                }
            mx = fmaxf(mx, __shfl_xor(mx, 16));
            mx = fmaxf(mx, __shfl_xor(mx, 32));
            const float mn = fmaxf(mrow, mx);
            const float sc = __expf(mrow - mn);
            float rs = 0.f;
            #pragma unroll
            for (int nt = 0; nt < 4; ++nt)
                #pragma unroll
                for (int r = 0; r < 4; ++r) {
                    float e = __expf(ev[nt][r] - mn);
                    ev[nt][r] = e; rs += e;
                }
            rs += __shfl_xor(rs, 16);
            rs += __shfl_xor(rs, 32);
            mrow = mn;
            lrow = lrow * sc + rs;
            #pragma unroll
            for (int nt = 0; nt < 4; ++nt) {
                bf16x4 pk = {(bf16_t)ev[nt][0], (bf16_t)ev[nt][1], (bf16_t)ev[nt][2], (bf16_t)ev[nt][3]};
                *(bf16x4*)&Plw[l15 * PITCH_P + nt * 16 + lg * 4] = pk;
            }
            float scb[4];
            #pragma unroll
            for (int r = 0; r < 4; ++r) scb[r] = __shfl(sc, lg * 4 + r);
            #pragma unroll
            for (int nt2 = 0; nt2 < 8; ++nt2)
                #pragma unroll
                for (int r = 0; r < 4; ++r) acc_o[nt2][r] *= scb[r];
            #pragma unroll
            for (int kc = 0; kc < 2; ++kc) {
                bf16x8 pf = *(const bf16x8*)&Plw[l15 * PITCH_P + kc * 32 + lg * 8];
                #pragma unroll
                for (int nt2 = 0; nt2 < 8; ++nt2) {
                    const int drow = nt2 * 16 + l15;
                    bf16x8 vf = *(const bf16x8*)&Vt[drow * 64 + (((kc * 4 + lg) ^ (drow & 7)) << 3)];
                    acc_o[nt2] = __builtin_amdgcn_mfma_f32_16x16x32_bf16(pf, vf, acc_o[nt2], 0, 0, 0);
                }
            }
        }
        float lb[4];
        #pragma unroll
        for (int r = 0; r < 4; ++r) lb[r] = __shfl(lrow, lg * 4 + r);
        #pragma unroll
        for (int nt2 = 0; nt2 < 8; ++nt2)
            #pragma unroll
            for (int r = 0; r < 4; ++r) {
                int q = q0 + w * 16 + lg * 4 + r;
                int d = nt2 * 16 + l15;
                O[((size_t)(b * S_LEN + q)) * (NH * HD) + h * HD + d] = (bf16_t)(acc_o[nt2][r] / lb[r]);
            }
    }
}

// ---------------- launch ----------------
extern "C" void kernel_launch(void* const* d_in, const int* in_sizes, int n_in,
                              void* d_out, int out_size, void* d_ws, size_t ws_size,
                              hipStream_t stream) {
    const float* hs   = (const float*)d_in[0];
    const float* cosb = (const float*)d_in[1];
    const float* sinb = (const float*)d_in[2];
    const float* wq   = (const float*)d_in[3];
    const float* wk   = (const float*)d_in[4];
    const float* wv   = (const float*)d_in[5];
    const float* wo   = (const float*)d_in[6];
    float* out = (float*)d_out;

    const size_t NHS = (size_t)B_SZ * S_LEN * HID;
    const size_t NQKVW = (size_t)QKV_N * HID;
    size_t need = (NHS * 3 + NQKVW * 2) * sizeof(bf16_t);
    if (ws_size < need) return;

    bf16_t* p = (bf16_t*)d_ws;
    bf16_t* hsb  = p; p += NHS;
    bf16_t* wqkv = p; p += NQKVW;
    bf16_t* wob  = p; p += NHS;
    bf16_t* QKVb = p; p += NQKVW;
    bf16_t* Ab   = p; p += NHS;

    auto cvt = [&](const float* src, bf16_t* dst, size_t n) {
        int n4 = (int)(n / 4);
        f2b_kernel<<<(n4 + 255) / 256, 256, 0, stream>>>((const float4*)src, (bf16x4*)dst, n4);
    };
    cvt(hs, hsb, NHS);
    cvt(wq, wqkv, NHS);
    cvt(wk, wqkv + (size_t)HID * HID, (size_t)NKV * HD * HID);
    cvt(wv, wqkv + (size_t)(HID + NKV * HD) * HID, (size_t)NKV * HD * HID);
    cvt(wo, wob, NHS);

    const int M = B_SZ * S_LEN;  // 4096
    // QKV: 32 x 24 = 768 blocks (3/CU); WO: 32 x 16 = 512 blocks (2/CU); both % 8 == 0
    gemm128<false><<<(M / 128) * (QKV_N / 256), 256, 0, stream>>>(hsb, wqkv, QKVb, M, QKV_N, HID);

    int rope_threads = B_SZ * S_LEN * (NH + NKV) * 64;
    rope_kernel<<<rope_threads / 256, 256, 0, stream>>>(QKVb, cosb, sinb);

    attn_fwd<<<dim3(16, NH, B_SZ), 256, 0, stream>>>(QKVb, Ab);

    gemm128<true><<<(M / 128) * (HID / 256), 256, 0, stream>>>(Ab, wob, out, M, HID, HID);
}

// Round 6
// 563.671 us; speedup vs baseline: 1.0802x; 1.0802x over previous
//
#include <hip/hip_runtime.h>
#include <stdint.h>

typedef __bf16 bf16_t;
typedef __bf16 bf16x8 __attribute__((ext_vector_type(8)));
typedef __bf16 bf16x4 __attribute__((ext_vector_type(4)));
typedef float f32x4 __attribute__((ext_vector_type(4)));

#define S_LEN 2048
#define NH 32
#define NKV 8
#define HD 128
#define B_SZ 2
#define HID 4096
#define QKV_N 6144
#define INFF __builtin_inff()

// global -> LDS direct copy, 16B per lane. LDS dest must be wave-uniform base + lane*16.
__device__ __forceinline__ void gload_lds16(const void* g, void* l) {
    __builtin_amdgcn_global_load_lds(
        (const __attribute__((address_space(1))) void*)(uintptr_t)g,
        (__attribute__((address_space(3))) void*)(uint32_t)(uintptr_t)l,
        16, 0, 0);
}

// ---------------- fp32 -> bf16 convert ----------------
__global__ __launch_bounds__(256) void f2b_kernel(const float4* __restrict__ in,
                                                  bf16x4* __restrict__ out, int n4) {
    int i = blockIdx.x * blockDim.x + threadIdx.x;
    if (i >= n4) return;
    float4 v = in[i];
    bf16x4 o = {(bf16_t)v.x, (bf16_t)v.y, (bf16_t)v.z, (bf16_t)v.w};
    out[i] = o;
}

// ---------------- GEMM 256x256 tile, 8-wave, 4-slot ring, counted vmcnt ----------------
// C[M,Nloc] = A[M,K] @ W[Nloc,K]^T over K-range [kOff, kOff+Kloc).
// blockIdx.y selects K-half (split-K): z=0 -> C0/ld0, z=1 -> C1/ld1.
#define SLOT_E 16384   // elems per slot (A 8192 + B 8192)

#define GTILE(T, STAGE, VMW) do {                                                         \
    const int _sb = ((T) & 3) * SLOT_E;                                                   \
    bf16x8 af[8], bfr[2];                                                                 \
    _Pragma("unroll") for (int i = 0; i < 8; ++i)                                         \
        af[i] = *(const bf16x8*)&lds[_sb + offA[i]];                                      \
    bfr[0] = *(const bf16x8*)&lds[_sb + 8192 + offB[0]];                                  \
    bfr[1] = *(const bf16x8*)&lds[_sb + 8192 + offB[1]];                                  \
    if (STAGE) {                                                                          \
        const int _ss = (((T) + 3) & 3) * SLOT_E;                                         \
        gload_lds16(sA0, &lds[_ss + ldsO0]); gload_lds16(sA1, &lds[_ss + ldsO1]);         \
        sA0 += 32; sA1 += 32;                                                             \
    }                                                                                     \
    __builtin_amdgcn_s_barrier();                                                         \
    asm volatile("s_waitcnt lgkmcnt(0)" ::: "memory");                                    \
    __builtin_amdgcn_sched_barrier(0);                                                    \
    __builtin_amdgcn_s_setprio(1);                                                        \
    _Pragma("unroll") for (int i = 0; i < 8; ++i) {                                       \
        acc[i][0] = __builtin_amdgcn_mfma_f32_16x16x32_bf16(af[i], bfr[0], acc[i][0], 0, 0, 0); \
        acc[i][1] = __builtin_amdgcn_mfma_f32_16x16x32_bf16(af[i], bfr[1], acc[i][1], 0, 0, 0); \
    }                                                                                     \
    __builtin_amdgcn_s_setprio(0);                                                        \
    __builtin_amdgcn_s_barrier();                                                         \
    bf16x8 bfs[2];                                                                        \
    bfs[0] = *(const bf16x8*)&lds[_sb + 8192 + offB[2]];                                  \
    bfs[1] = *(const bf16x8*)&lds[_sb + 8192 + offB[3]];                                  \
    if (STAGE) {                                                                          \
        const int _ss = (((T) + 3) & 3) * SLOT_E;                                         \
        gload_lds16(sB0, &lds[_ss + 8192 + ldsO0]); gload_lds16(sB1, &lds[_ss + 8192 + ldsO1]); \
        sB0 += 32; sB1 += 32;                                                             \
    }                                                                                     \
    __builtin_amdgcn_s_barrier();                                                         \
    asm volatile("s_waitcnt lgkmcnt(0)" ::: "memory");                                    \
    __builtin_amdgcn_sched_barrier(0);                                                    \
    __builtin_amdgcn_s_setprio(1);                                                        \
    _Pragma("unroll") for (int i = 0; i < 8; ++i) {                                       \
        acc[i][2] = __builtin_amdgcn_mfma_f32_16x16x32_bf16(af[i], bfs[0], acc[i][2], 0, 0, 0); \
        acc[i][3] = __builtin_amdgcn_mfma_f32_16x16x32_bf16(af[i], bfs[1], acc[i][3], 0, 0, 0); \
    }                                                                                     \
    __builtin_amdgcn_s_setprio(0);                                                        \
    if ((VMW) == 8)      asm volatile("s_waitcnt vmcnt(8)" ::: "memory");                 \
    else if ((VMW) == 4) asm volatile("s_waitcnt vmcnt(4)" ::: "memory");                 \
    else if ((VMW) == 0) asm volatile("s_waitcnt vmcnt(0)" ::: "memory");                 \
    __builtin_amdgcn_s_barrier();                                                         \
} while (0)

template<bool F32OUT>
__global__ __launch_bounds__(512, 2) void gemm256(const bf16_t* __restrict__ A,
                                                  const bf16_t* __restrict__ W,
                                                  void* __restrict__ C0,
                                                  void* __restrict__ C1,
                                                  int ld0, int ld1,
                                                  int Nloc, int ldAW, int Kloc) {
    __shared__ __align__(16) bf16_t lds[4 * SLOT_E];   // 128 KB
    const int tid = threadIdx.x;
    const int lane = tid & 63;
    const int w = tid >> 6;
    const int wm = w >> 2, wn = w & 3;
    const int l15 = lane & 15, lg = lane >> 4;

    const int z = blockIdx.y;
    void* Cv = z ? C1 : C0;
    const int ldC = z ? ld1 : ld0;
    const int kOff = z * Kloc;

    // XCD-aware block swizzle (gridDim.x % 8 == 0)
    const int nbx = Nloc >> 8;
    const int cpx = gridDim.x >> 3;
    const int bid = blockIdx.x;
    const int bid2 = (bid & 7) * cpx + (bid >> 3);
    const int m0 = (bid2 / nbx) * 256;
    const int n0 = (bid2 % nbx) * 256;

    // staging: chunk c -> row=c>>2, src col chunk (c&3)^((row>>1)&3); LDS linear at c*16B
    const int c0 = tid, c1 = 512 + tid;
    const int rA0 = c0 >> 2, ch0 = (c0 & 3) ^ ((rA0 >> 1) & 3);
    const int rA1 = c1 >> 2, ch1 = (c1 & 3) ^ ((rA1 >> 1) & 3);
    const bf16_t* sA0 = A + (size_t)(m0 + rA0) * ldAW + kOff + ch0 * 8;
    const bf16_t* sA1 = A + (size_t)(m0 + rA1) * ldAW + kOff + ch1 * 8;
    const bf16_t* sB0 = W + (size_t)(n0 + rA0) * ldAW + kOff + ch0 * 8;
    const bf16_t* sB1 = W + (size_t)(n0 + rA1) * ldAW + kOff + ch1 * 8;
    const int ldsO0 = c0 * 8, ldsO1 = c1 * 8;

    int offA[8], offB[4];
    #pragma unroll
    for (int i = 0; i < 8; ++i) {
        int row = wm * 128 + i * 16 + l15;
        offA[i] = row * 32 + ((lg ^ ((row >> 1) & 3)) * 8);
    }
    #pragma unroll
    for (int j = 0; j < 4; ++j) {
        int row = wn * 64 + j * 16 + l15;
        offB[j] = row * 32 + ((lg ^ ((row >> 1) & 3)) * 8);
    }

    #pragma unroll
    for (int tt = 0; tt < 3; ++tt) {
        const int ss = tt * SLOT_E;
        gload_lds16(sA0, &lds[ss + ldsO0]); gload_lds16(sA1, &lds[ss + ldsO1]);
        gload_lds16(sB0, &lds[ss + 8192 + ldsO0]); gload_lds16(sB1, &lds[ss + 8192 + ldsO1]);
        sA0 += 32; sA1 += 32; sB0 += 32; sB1 += 32;
    }
    asm volatile("s_waitcnt vmcnt(8)" ::: "memory");
    __builtin_amdgcn_s_barrier();

    f32x4 acc[8][4] = {};
    const int NT = Kloc >> 5;
    int t = 0;
    for (; t < NT - 3; ++t) GTILE(t, true, 8);
    GTILE(NT - 3, false, 4);
    GTILE(NT - 2, false, 0);
    GTILE(NT - 1, false, -1);

    #pragma unroll
    for (int i = 0; i < 8; ++i)
        #pragma unroll
        for (int jn = 0; jn < 4; ++jn)
            #pragma unroll
            for (int r = 0; r < 4; ++r) {
                int m = m0 + wm * 128 + i * 16 + lg * 4 + r;
                int n = n0 + wn * 64 + jn * 16 + l15;
                float v = acc[i][jn][r];
                if (F32OUT) ((float*)Cv)[(size_t)m * ldC + n] = v;
                else        ((bf16_t*)Cv)[(size_t)m * ldC + n] = (bf16_t)v;
            }
}

// ---------------- Fused split-K reduce + RoPE ----------------
// 48 head-groups: 0..31 Q (rope), 32..39 K (sum P1 + rope), 40..47 V (sum P1 only).
__global__ __launch_bounds__(256) void rope_fuse(bf16_t* __restrict__ QKV,
                                                 const bf16_t* __restrict__ P1,
                                                 const float* __restrict__ cosb,
                                                 const float* __restrict__ sinb) {
    int tid = blockIdx.x * blockDim.x + threadIdx.x;   // 4096*48*64 threads
    int d = tid & 63;
    int hg = (tid >> 6) % 48;
    int bs = tid / (64 * 48);
    bf16_t* rowp;
    float x1, x2;
    if (hg < 32) {
        rowp = QKV + (size_t)bs * QKV_N + hg * HD;
        x1 = (float)rowp[d];
        x2 = (float)rowp[d + 64];
    } else if (hg < 40) {
        int col = HID + (hg - 32) * HD;
        rowp = QKV + (size_t)bs * QKV_N + col;
        const bf16_t* pp = P1 + (size_t)bs * 2048 + (col - HID);
        x1 = (float)rowp[d] + (float)pp[d];
        x2 = (float)rowp[d + 64] + (float)pp[d + 64];
    } else {
        int col = HID + NKV * HD + (hg - 40) * HD;
        rowp = QKV + (size_t)bs * QKV_N + col;
        const bf16_t* pp = P1 + (size_t)bs * 2048 + (col - HID);
        rowp[d]      = (bf16_t)((float)rowp[d]      + (float)pp[d]);
        rowp[d + 64] = (bf16_t)((float)rowp[d + 64] + (float)pp[d + 64]);
        return;
    }
    float c1 = cosb[(size_t)bs * HD + d];
    float s1 = sinb[(size_t)bs * HD + d];
    float c2 = cosb[(size_t)bs * HD + d + 64];
    float s2 = sinb[(size_t)bs * HD + d + 64];
    rowp[d]      = (bf16_t)(x1 * c1 - x2 * s1);
    rowp[d + 64] = (bf16_t)(x2 * c2 + x1 * s2);
}

// ---------------- Flash attention: QB=64 (4 waves), KB=64, dbuf K/V, defer-max ----------------
#define PITCH_P 72

__global__ __launch_bounds__(256, 2) void attn_fwd(const bf16_t* __restrict__ QKV,
                                                   bf16_t* __restrict__ O) {
    __shared__ __align__(16) bf16_t Kl[2][64 * 128];      // 32KB, chunk^=(k&7)
    __shared__ __align__(16) bf16_t Vt[2][128 * 64];      // 32KB, chunk^=(d&7)
    __shared__ __align__(16) bf16_t Pl[4][16 * PITCH_P];  // 9KB per-wave P
    const int tid = threadIdx.x;
    const int lane = tid & 63;
    const int w = tid >> 6;
    const int l15 = lane & 15, lg = lane >> 4;
    const int pr = blockIdx.x, h = blockIdx.y, b = blockIdx.z;
    const int kvh = h >> 2;
    const float scale = 0.08838834764831845f;

    int krow[4], kch[4];
    for (int jj = 0; jj < 4; ++jj) { int q = jj * 256 + tid; krow[jj] = q >> 4; kch[jj] = q & 15; }
    const int d0 = (tid >> 4) * 8;
    const int k0v = (tid & 15) * 4;
    const int vci = k0v >> 3;
    const int vsub = k0v & 7;

    const bf16_t* Kb0 = QKV + (size_t)(b * S_LEN) * QKV_N + HID + kvh * HD;
    const bf16_t* Vb0 = QKV + (size_t)(b * S_LEN) * QKV_N + HID + NKV * HD + kvh * HD;
    bf16_t* Plw = Pl[w];

    for (int t = 0; t < 2; ++t) {
        const int qt = (t == 0) ? pr : (31 - pr);   // paired tiles -> 33 steps/block
        const int q0 = qt * 64;
        const int qrow = q0 + w * 16 + l15;

        bf16x8 qf[4];
        {
            const bf16_t* qp = QKV + (size_t)(b * S_LEN + qrow) * QKV_N + h * HD;
            for (int c = 0; c < 4; ++c) qf[c] = *(const bf16x8*)&qp[c * 32 + lg * 8];
        }

        f32x4 acc_o[8] = {};
        float mrow = -INFF, lrow = 0.f;
        const int nsteps = qt + 1;

        bf16x8 kst[4], vst[4];
        for (int jj = 0; jj < 4; ++jj)
            kst[jj] = *(const bf16x8*)&Kb0[(size_t)krow[jj] * QKV_N + kch[jj] * 8];
        for (int j2 = 0; j2 < 4; ++j2)
            vst[j2] = *(const bf16x8*)&Vb0[(size_t)(k0v + j2) * QKV_N + d0];

        __syncthreads();   // all waves done reading LDS from previous q-tile

        for (int st = 0; st < nsteps; ++st) {
            const int k0 = st * 64;
            const int p = st & 1;
            // write staged regs -> LDS buffer p (buffer p's previous readers finished
            // before the barrier at the end of step st-1's write phase)
            for (int jj = 0; jj < 4; ++jj)
                *(bf16x8*)&Kl[p][krow[jj] * 128 + ((kch[jj] ^ (krow[jj] & 7)) * 8)] = kst[jj];
            #pragma unroll
            for (int j = 0; j < 8; ++j) {
                bf16x4 cvec = { vst[0][j], vst[1][j], vst[2][j], vst[3][j] };
                *(bf16x4*)&Vt[p][(d0 + j) * 64 + ((vci ^ j) << 3) + vsub] = cvec;
            }
            __syncthreads();   // buffer p visible to all waves
            if (st + 1 < nsteps) {   // prefetch next tile into regs (hides under compute)
                const bf16_t* Kb = Kb0 + (size_t)(k0 + 64) * QKV_N;
                const bf16_t* Vb = Vb0 + (size_t)(k0 + 64) * QKV_N;
                for (int jj = 0; jj < 4; ++jj)
                    kst[jj] = *(const bf16x8*)&Kb[(size_t)krow[jj] * QKV_N + kch[jj] * 8];
                for (int j2 = 0; j2 < 4; ++j2)
                    vst[j2] = *(const bf16x8*)&Vb[(size_t)(k0v + j2) * QKV_N + d0];
            }
            // QK^T swapped: s[nt] = K x Q -> lane holds S[k=nt*16+lg*4+r][q=l15]
            f32x4 s[4];
            #pragma unroll
            for (int nt = 0; nt < 4; ++nt) {
                s[nt] = (f32x4){0.f, 0.f, 0.f, 0.f};
                const int row = nt * 16 + l15;
                const int rb = row * 128, key = row & 7;
                #pragma unroll
                for (int c = 0; c < 4; ++c) {
                    bf16x8 kf = *(const bf16x8*)&Kl[p][rb + (((c * 4 + lg) ^ key) * 8)];
                    s[nt] = __builtin_amdgcn_mfma_f32_16x16x32_bf16(kf, qf[c], s[nt], 0, 0, 0);
                }
            }
            // softmax for q=qrow (16 scores/lane) with defer-max
            float ev[4][4];
            float mx = -INFF;
            #pragma unroll
            for (int nt = 0; nt < 4; ++nt)
                #pragma unroll
                for (int r = 0; r < 4; ++r) {
                    int k = k0 + nt * 16 + lg * 4 + r;
                    float v = (k <= qrow) ? s[nt][r] * scale : -INFF;
                    ev[nt][r] = v;
                    mx = fmaxf(mx, v);
                }
            mx = fmaxf(mx, __shfl_xor(mx, 16));
            mx = fmaxf(mx, __shfl_xor(mx, 32));
            const bool nodefer = !__all(mx <= mrow + 8.f);
            float mn, sc;
            if (nodefer) { mn = fmaxf(mrow, mx); sc = __expf(mrow - mn); }
            else         { mn = mrow;            sc = 1.f; }
            float rs = 0.f;
            #pragma unroll
            for (int nt = 0; nt < 4; ++nt)
                #pragma unroll
                for (int r = 0; r < 4; ++r) {
                    float e = __expf(ev[nt][r] - mn);
                    ev[nt][r] = e; rs += e;
                }
            rs += __shfl_xor(rs, 16);
            rs += __shfl_xor(rs, 32);
            mrow = mn;
            lrow = lrow * sc + rs;
            #pragma unroll
            for (int nt = 0; nt < 4; ++nt) {
                bf16x4 pk = {(bf16_t)ev[nt][0], (bf16_t)ev[nt][1], (bf16_t)ev[nt][2], (bf16_t)ev[nt][3]};
                *(bf16x4*)&Plw[l15 * PITCH_P + nt * 16 + lg * 4] = pk;
            }
            if (nodefer) {
                float scb[4];
                #pragma unroll
                for (int r = 0; r < 4; ++r) scb[r] = __shfl(sc, lg * 4 + r);
                #pragma unroll
                for (int nt2 = 0; nt2 < 8; ++nt2)
                    #pragma unroll
                    for (int r = 0; r < 4; ++r) acc_o[nt2][r] *= scb[r];
            }
            // PV: A=P[q][k] (row l15), B=Vt[d][k]
            #pragma unroll
            for (int kc = 0; kc < 2; ++kc) {
                bf16x8 pf = *(const bf16x8*)&Plw[l15 * PITCH_P + kc * 32 + lg * 8];
                #pragma unroll
                for (int nt2 = 0; nt2 < 8; ++nt2) {
                    const int drow = nt2 * 16 + l15;
                    bf16x8 vf = *(const bf16x8*)&Vt[p][drow * 64 + (((kc * 4 + lg) ^ (drow & 7)) << 3)];
                    acc_o[nt2] = __builtin_amdgcn_mfma_f32_16x16x32_bf16(pf, vf, acc_o[nt2], 0, 0, 0);
                }
            }
        }
        // epilogue
        float lb[4];
        #pragma unroll
        for (int r = 0; r < 4; ++r) lb[r] = __shfl(lrow, lg * 4 + r);
        #pragma unroll
        for (int nt2 = 0; nt2 < 8; ++nt2)
            #pragma unroll
            for (int r = 0; r < 4; ++r) {
                int q = q0 + w * 16 + lg * 4 + r;
                int d = nt2 * 16 + l15;
                O[((size_t)(b * S_LEN + q)) * (NH * HD) + h * HD + d] = (bf16_t)(acc_o[nt2][r] / lb[r]);
            }
    }
}

// ---------------- launch ----------------
extern "C" void kernel_launch(void* const* d_in, const int* in_sizes, int n_in,
                              void* d_out, int out_size, void* d_ws, size_t ws_size,
                              hipStream_t stream) {
    const float* hs   = (const float*)d_in[0];
    const float* cosb = (const float*)d_in[1];
    const float* sinb = (const float*)d_in[2];
    const float* wq   = (const float*)d_in[3];
    const float* wk   = (const float*)d_in[4];
    const float* wv   = (const float*)d_in[5];
    const float* wo   = (const float*)d_in[6];
    float* out = (float*)d_out;

    const size_t NHS = (size_t)B_SZ * S_LEN * HID;
    const size_t NQKVW = (size_t)QKV_N * HID;
    size_t need = (NHS * 3 + NQKVW * 2) * sizeof(bf16_t);
    if (ws_size < need) return;

    bf16_t* p = (bf16_t*)d_ws;
    bf16_t* hsb  = p; p += NHS;     // [4096][4096]
    bf16_t* wqkv = p; p += NQKVW;   // [6144][4096]
    bf16_t* wob  = p; p += NHS;     // [4096][4096]
    bf16_t* QKVb = p; p += NQKVW;   // [4096][6144]
    bf16_t* Ab   = p; p += NHS;     // [4096][4096]; doubles as P1 [4096][2048] pre-attention
    bf16_t* P1   = Ab;              // disjoint lifetime: P1 dies at rope_fuse, Ab born at attn

    auto cvt = [&](const float* src, bf16_t* dst, size_t n) {
        int n4 = (int)(n / 4);
        f2b_kernel<<<(n4 + 255) / 256, 256, 0, stream>>>((const float4*)src, (bf16x4*)dst, n4);
    };
    cvt(hs, hsb, NHS);
    cvt(wq, wqkv, NHS);
    cvt(wk, wqkv + (size_t)HID * HID, (size_t)NKV * HD * HID);
    cvt(wv, wqkv + (size_t)(HID + NKV * HD) * HID, (size_t)NKV * HD * HID);
    cvt(wo, wob, NHS);

    // QKV projection, tail-free:
    //  L1: cols 0..4095, full K -> 16x16=256 blocks (1 exact round)
    gemm256<false><<<dim3(256, 1), 512, 0, stream>>>(hsb, wqkv, QKVb, QKVb,
                                                     QKV_N, QKV_N, 4096, HID, HID);
    //  L2: cols 4096..6143, split-K=2 -> (16x8)x2=256 blocks (~0.5 round)
    gemm256<false><<<dim3(128, 2), 512, 0, stream>>>(hsb, wqkv + (size_t)HID * HID,
                                                     QKVb + HID, P1,
                                                     QKV_N, 2048, 2048, HID, 2048);

    // fused split-K reduce + RoPE
    int rf_threads = B_SZ * S_LEN * 48 * 64;
    rope_fuse<<<rf_threads / 256, 256, 0, stream>>>(QKVb, P1, cosb, sinb);

    attn_fwd<<<dim3(16, NH, B_SZ), 256, 0, stream>>>(QKVb, Ab);

    gemm256<true><<<dim3(256, 1), 512, 0, stream>>>(Ab, wob, out, out,
                                                    HID, HID, HID, HID, HID);
}